// Round 5
// baseline (97.318 us; speedup 1.0000x reference)
//
#include <hip/hip_runtime.h>
#include <hip/hip_bf16.h>

// MemoryEfficientAttention round 5:
//  - 4-wave blocks, QBLK=128, grid 512 -> 2 blocks/CU: two independent barrier
//    domains per CU (cross-block overlap hides softmax chain + barrier drain)
//  - P pack via v_permlane32_swap_b32 (T12): kills 8 ds_bpermute + ~32 cndmask
//    per tile (the 2^22 bank-conflict source) -> pack is pure VALU
//  - otherwise round-4 structure: swapped-QK 32x32 MFMA, in-register softmax,
//    pre-transposed bf16 K/V in ws, global_load_lds staging, 2-phase dbuf

typedef short short8 __attribute__((ext_vector_type(8)));
typedef float f32x16 __attribute__((ext_vector_type(16)));

#define MFMA32(a, b, c) __builtin_amdgcn_mfma_f32_32x32x16_bf16((a), (b), (c), 0, 0, 0)

#if __has_builtin(__builtin_amdgcn_exp2f)
#define EXP2(x) __builtin_amdgcn_exp2f(x)
#else
#define EXP2(x) exp2f(x)
#endif

constexpr int Dh  = 128;
constexpr int S_  = 2048;
constexpr int KVB = 64;
constexpr int NT  = S_ / KVB;          // 32 kv tiles
constexpr int WAVES = 4;
constexpr int QBLK  = 128;             // 4 waves x 32 q-rows

__device__ __forceinline__ short f2bf(float f) {
    union { float f; unsigned u; } x; x.f = f;
    unsigned r = x.u + 0x7fffu + ((x.u >> 16) & 1u);   // RNE
    return (short)(r >> 16);
}

// packed RNE f32x2 -> bf16x2
__device__ __forceinline__ unsigned pkbf(float lo, float hi) {
    unsigned r;
    asm("v_cvt_pk_bf16_f32 %0, %1, %2" : "=v"(r) : "v"(lo), "v"(hi));
    return r;
}

// v_permlane32_swap_b32: a.row1 <-> b.row0  (rows = lane<32 / lane>=32)
__device__ __forceinline__ void pswap(unsigned &a, unsigned &b) {
    asm("v_permlane32_swap_b32 %0, %1" : "+v"(a), "+v"(b));
}

__device__ __forceinline__ void gload16(const void* g, void* l) {
    __builtin_amdgcn_global_load_lds(
        (const __attribute__((address_space(1))) unsigned int*)g,
        (__attribute__((address_space(3))) unsigned int*)l, 16, 0, 0);
}

// ---------------- pre-pass: K fp32 -> bf16, 16B blocks XOR'd by row&15 -----
__global__ __launch_bounds__(256) void prep_k(const float* __restrict__ K,
                                              short* __restrict__ Kz) {
    int idx = blockIdx.x * 256 + threadIdx.x;     // one 16B out block
    int b   = idx & 15;
    int s   = (idx >> 4) & (S_ - 1);
    int sb  = b ^ (s & 15);
    const float* src = K + (size_t)(idx >> 4) * Dh + sb * 8;
    float4 f0 = ((const float4*)src)[0];
    float4 f1 = ((const float4*)src)[1];
    short8 o;
    o[0] = f2bf(f0.x); o[1] = f2bf(f0.y); o[2] = f2bf(f0.z); o[3] = f2bf(f0.w);
    o[4] = f2bf(f1.x); o[5] = f2bf(f1.y); o[6] = f2bf(f1.z); o[7] = f2bf(f1.w);
    *(short8*)(Kz + (size_t)idx * 8) = o;
}

// ---------------- pre-pass: V fp32 -> bf16 transposed tiles ----------------
// Vt[bh][seg][d][64]: row d holds V[seg*64 .. +63][d]; 16B block j stores
// s-block (j ^ (d&7)).
__global__ __launch_bounds__(256) void prep_v(const float* __restrict__ V,
                                              short* __restrict__ Vt) {
    __shared__ short tr[64][72];
    int bid = blockIdx.x;
    int dg = bid & 1, seg = (bid >> 1) & 31, bh = bid >> 6;
    int t = threadIdx.x;
    int s = t >> 2, d0 = (t & 3) * 16;
    const float* src = V + (size_t)(bh * S_ + seg * 64 + s) * Dh + dg * 64 + d0;
    #pragma unroll
    for (int i = 0; i < 16; i += 4) {
        float4 f = *(const float4*)(src + i);
        tr[d0 + i + 0][s] = f2bf(f.x); tr[d0 + i + 1][s] = f2bf(f.y);
        tr[d0 + i + 2][s] = f2bf(f.z); tr[d0 + i + 3][s] = f2bf(f.w);
    }
    __syncthreads();
    int d = t >> 2, j0 = (t & 3) * 2;
    size_t ob = ((size_t)(bh * 32 + seg) * 128 + dg * 64 + d) * 64;
    #pragma unroll
    for (int jj = 0; jj < 2; ++jj) {
        int j = j0 + jj;
        int sj = (j ^ (d & 7)) * 8;
        short8 val = *(const short8*)&tr[d][sj];
        *(short8*)(Vt + ob + j * 8) = val;
    }
}

// ---------------- main flash kernel (4-wave, 32x32, swapped QK) ------------
__global__ __launch_bounds__(256, 2)
void mea_fwd5(const float* __restrict__ Qg, const short* __restrict__ Kz,
              const short* __restrict__ Vt, float* __restrict__ Og, int nqt) {
    __shared__ __align__(16) short k0[KVB * Dh], k1[KVB * Dh];
    __shared__ __align__(16) short v0[Dh * KVB], v1[Dh * KVB];
    __shared__ float bc_lds[WAVES][32];    // rare-path row broadcast

    // bijective XCD swizzle (grid % 8 == 0): 4 bh per XCD -> KV fits its L2
    const int bid = blockIdx.x;
    const int cpx = (int)gridDim.x >> 3;
    const int swz = (bid & 7) * cpx + (bid >> 3);
    const int qt  = swz % nqt;
    const int bh  = swz / nqt;

    const int tid  = threadIdx.x;
    const int w    = tid >> 6;
    const int lane = tid & 63;
    const int l31  = lane & 31;
    const int hi   = lane >> 5;

    const size_t base = (size_t)bh * S_ * Dh;
    const int    qrow = qt * QBLK + w * 32 + l31;   // this lane's softmax row
    const float  QSC  = 0.08838834764831845f * 1.4426950408889634f; // scale*log2e

    // ---- Q B-frags: lane holds Q[qrow][kc*16 + hi*8 .. +7], pre-scaled ----
    short8 qf[8];
    {
        const float* qp = Qg + base + (size_t)qrow * Dh;
        #pragma unroll
        for (int kc = 0; kc < 8; ++kc) {
            const float4 f0 = *(const float4*)(qp + kc * 16 + hi * 8);
            const float4 f1 = *(const float4*)(qp + kc * 16 + hi * 8 + 4);
            short8 a;
            a[0] = f2bf(f0.x * QSC); a[1] = f2bf(f0.y * QSC);
            a[2] = f2bf(f0.z * QSC); a[3] = f2bf(f0.w * QSC);
            a[4] = f2bf(f1.x * QSC); a[5] = f2bf(f1.y * QSC);
            a[6] = f2bf(f1.z * QSC); a[7] = f2bf(f1.w * QSC);
            qf[kc] = a;
        }
    }

    f32x16 oacc[4];
    #pragma unroll
    for (int dt = 0; dt < 4; ++dt)
        #pragma unroll
        for (int r = 0; r < 16; ++r) oacc[dt][r] = 0.f;
    float mrun = -1e30f, lpart = 0.f;

    const short* kt0 = Kz + base;           // [64 kv][128 d] tiles, contiguous
    const short* vt0 = Vt + base;           // [128 d][64 kv] tiles, contiguous

    auto STAGE = [&](short* kl, short* vl, int t) {
        const short* ks = kt0 + (size_t)t * (KVB * Dh);
        const short* vs = vt0 + (size_t)t * (Dh * KVB);
        #pragma unroll
        for (int i = 0; i < 4; ++i) {
            const int ou = (i * 4 + w) * 512;        // wave-uniform LDS offset
            gload16(ks + ou + lane * 8, kl + ou);
            gload16(vs + ou + lane * 8, vl + ou);
        }
    };

    auto COMPUTE = [&](const short* kl, const short* vl) {
        // ---- S^T = K Q : two kv-half 32x32 tiles, D=128 via 8 MFMA each ----
        f32x16 sa, sb;
        #pragma unroll
        for (int r = 0; r < 16; ++r) { sa[r] = 0.f; sb[r] = 0.f; }
        __builtin_amdgcn_s_setprio(1);
        #pragma unroll
        for (int kc = 0; kc < 8; ++kc) {
            const int go = (((kc * 2 + hi) ^ (l31 & 15)) * 8);
            const short8 a0 = *(const short8*)&kl[l31 * Dh + go];
            const short8 a1 = *(const short8*)&kl[(32 + l31) * Dh + go];
            sa = MFMA32(a0, qf[kc], sa);
            sb = MFMA32(a1, qf[kc], sb);
        }
        __builtin_amdgcn_s_setprio(0);

        // ---- lane-local softmax (q = l31), defer-max THR=8 ----
        float mxl = sa[0];
        #pragma unroll
        for (int r = 1; r < 16; ++r) mxl = fmaxf(mxl, sa[r]);
        #pragma unroll
        for (int r = 0; r < 16; ++r) mxl = fmaxf(mxl, sb[r]);
        if (__any(mxl > mrun + 8.0f)) {
            float mo   = fmaxf(mxl, __shfl_xor(mxl, 32));
            float mnew = fmaxf(mrun, mo);
            float rc   = EXP2(mrun - mnew);
            mrun = mnew;
            lpart *= rc;
            if (!hi) bc_lds[w][l31] = rc;
            // rescale O: rows (reg&3)+8*(reg>>2)+4*hi -> quads at m*8+4hi
            #pragma unroll
            for (int m = 0; m < 4; ++m) {
                const float4 rcv = *(const float4*)&bc_lds[w][m * 8 + 4 * hi];
                #pragma unroll
                for (int t2 = 0; t2 < 4; ++t2) {
                    const float f = (&rcv.x)[t2];
                    #pragma unroll
                    for (int dt = 0; dt < 4; ++dt) oacc[dt][m * 4 + t2] *= f;
                }
            }
        }

        // ---- P = exp2(S - m), in-register ----
        f32x16 pa, pb;
        float s0 = 0.f, s1 = 0.f;
        #pragma unroll
        for (int r = 0; r < 16; ++r) { pa[r] = EXP2(sa[r] - mrun); s0 += pa[r]; }
        #pragma unroll
        for (int r = 0; r < 16; ++r) { pb[r] = EXP2(sb[r] - mrun); s1 += pb[r]; }
        lpart += s0 + s1;

        // ---- pack to PV A-frags: 16 cvt_pk + 8 permlane32_swap (T12) ----
        short8 pf[4];
        {
            #pragma unroll
            for (int kk = 0; kk < 2; ++kk) {
                unsigned a0 = pkbf(pa[kk * 8 + 0], pa[kk * 8 + 1]);
                unsigned a1 = pkbf(pa[kk * 8 + 2], pa[kk * 8 + 3]);
                unsigned b0 = pkbf(pa[kk * 8 + 4], pa[kk * 8 + 5]);
                unsigned b1 = pkbf(pa[kk * 8 + 6], pa[kk * 8 + 7]);
                pswap(a0, b0); pswap(a1, b1);
                unsigned wd[4] = {a0, a1, b0, b1};
                pf[kk] = *(const short8*)wd;
            }
            #pragma unroll
            for (int kk = 0; kk < 2; ++kk) {
                unsigned a0 = pkbf(pb[kk * 8 + 0], pb[kk * 8 + 1]);
                unsigned a1 = pkbf(pb[kk * 8 + 2], pb[kk * 8 + 3]);
                unsigned b0 = pkbf(pb[kk * 8 + 4], pb[kk * 8 + 5]);
                unsigned b1 = pkbf(pb[kk * 8 + 6], pb[kk * 8 + 7]);
                pswap(a0, b0); pswap(a1, b1);
                unsigned wd[4] = {a0, a1, b0, b1};
                pf[2 + kk] = *(const short8*)wd;
            }
        }

        // ---- O += P V : 4 d-tiles x 4 kv-slices = 16 MFMA ----
        __builtin_amdgcn_s_setprio(1);
        #pragma unroll
        for (int dt = 0; dt < 4; ++dt) {
            #pragma unroll
            for (int ks = 0; ks < 4; ++ks) {
                const short8 bv = *(const short8*)
                    &vl[(dt * 32 + l31) * KVB + (((ks * 2 + hi) ^ (l31 & 7)) * 8)];
                oacc[dt] = MFMA32(pf[ks], bv, oacc[dt]);
            }
        }
        __builtin_amdgcn_s_setprio(0);
    };

    // ---- 2-phase pipeline: stage t+1 before compute t, one barrier/tile ----
    STAGE(k0, v0, 0);
    __syncthreads();
    #pragma unroll 1
    for (int t = 0; t < NT; t += 2) {
        STAGE(k1, v1, t + 1);
        COMPUTE(k0, v0);
        __syncthreads();
        if (t + 2 < NT) STAGE(k0, v0, t + 2);
        COMPUTE(k1, v1);
        __syncthreads();
    }

    // ---- epilogue: total row sum via lane^32, broadcast 1/l, store ----
    {
        const float tot = lpart + __shfl_xor(lpart, 32);
        if (!hi) bc_lds[w][l31] = 1.0f / tot;
    }
    float* op = Og + base;
    #pragma unroll
    for (int m = 0; m < 4; ++m) {
        const float4 li = *(const float4*)&bc_lds[w][m * 8 + 4 * hi];
        #pragma unroll
        for (int t2 = 0; t2 < 4; ++t2) {
            const int row  = m * 8 + 4 * hi + t2;
            const float lf = (&li.x)[t2];
            #pragma unroll
            for (int dt = 0; dt < 4; ++dt)
                op[(size_t)(qt * QBLK + w * 32 + row) * Dh + dt * 32 + l31]
                    = oacc[dt][m * 4 + t2] * lf;
        }
    }
}

// ---------------- fallback (no-ws path) ------------------------------------
typedef float f32x4 __attribute__((ext_vector_type(4)));
#define MFMA16(a, b, c) __builtin_amdgcn_mfma_f32_16x16x32_bf16((a), (b), (c), 0, 0, 0)
constexpr int FKVB = 32;
constexpr int FKP  = 136;
constexpr int FVP  = 40;
constexpr int FPP  = 40;

__global__ __launch_bounds__(256, 2)
void mea_fwd_fb(const float* __restrict__ Qg, const float* __restrict__ Kg,
                const float* __restrict__ Vg, float* __restrict__ Og,
                int S, int nqt) {
    __shared__ __align__(16) short k_lds[FKVB][FKP];
    __shared__ __align__(16) short vT_lds[Dh][FVP];
    __shared__ __align__(16) short p_lds[4][16][FPP];

    const int qt = blockIdx.x % nqt;
    const int bh = blockIdx.x / nqt;
    const int tid = threadIdx.x;
    const int w = tid >> 6, lane = tid & 63;
    const int lr = lane & 15, lg = lane >> 4;
    const size_t base = (size_t)bh * S * Dh;
    const int qrow0 = qt * 64 + w * 16;
    const float scale = 0.08838834764831845f;

    short8 qf[4];
    {
        const float* qp = Qg + base + (size_t)(qrow0 + lr) * Dh;
        #pragma unroll
        for (int kc = 0; kc < 4; ++kc) {
            const float4 f0 = *(const float4*)(qp + kc * 32 + lg * 8);
            const float4 f1 = *(const float4*)(qp + kc * 32 + lg * 8 + 4);
            short8 a;
            a[0] = f2bf(f0.x); a[1] = f2bf(f0.y); a[2] = f2bf(f0.z); a[3] = f2bf(f0.w);
            a[4] = f2bf(f1.x); a[5] = f2bf(f1.y); a[6] = f2bf(f1.z); a[7] = f2bf(f1.w);
            qf[kc] = a;
        }
    }
    f32x4 oacc[8];
    #pragma unroll
    for (int dt = 0; dt < 8; ++dt) oacc[dt] = (f32x4){0.f, 0.f, 0.f, 0.f};
    float mrun[4] = {-1e30f, -1e30f, -1e30f, -1e30f};
    float lrun[4] = {0.f, 0.f, 0.f, 0.f};
    const int sr = tid >> 3, sc = (tid & 7) * 16;

    for (int kv0 = 0; kv0 < S; kv0 += FKVB) {
        {
            const float* kp = Kg + base + (size_t)(kv0 + sr) * Dh + sc;
            const float* vp = Vg + base + (size_t)(kv0 + sr) * Dh + sc;
            short8 pk0, pk1;
            float4 f0 = ((const float4*)kp)[0], f1 = ((const float4*)kp)[1];
            float4 f2 = ((const float4*)kp)[2], f3 = ((const float4*)kp)[3];
            pk0[0] = f2bf(f0.x); pk0[1] = f2bf(f0.y); pk0[2] = f2bf(f0.z); pk0[3] = f2bf(f0.w);
            pk0[4] = f2bf(f1.x); pk0[5] = f2bf(f1.y); pk0[6] = f2bf(f1.z); pk0[7] = f2bf(f1.w);
            pk1[0] = f2bf(f2.x); pk1[1] = f2bf(f2.y); pk1[2] = f2bf(f2.z); pk1[3] = f2bf(f2.w);
            pk1[4] = f2bf(f3.x); pk1[5] = f2bf(f3.y); pk1[6] = f2bf(f3.z); pk1[7] = f2bf(f3.w);
            *(short8*)&k_lds[sr][sc] = pk0;
            *(short8*)&k_lds[sr][sc + 8] = pk1;
            #pragma unroll
            for (int i = 0; i < 4; ++i) {
                float4 f = ((const float4*)vp)[i];
                vT_lds[sc + 4 * i + 0][sr] = f2bf(f.x);
                vT_lds[sc + 4 * i + 1][sr] = f2bf(f.y);
                vT_lds[sc + 4 * i + 2][sr] = f2bf(f.z);
                vT_lds[sc + 4 * i + 3][sr] = f2bf(f.w);
            }
        }
        __syncthreads();
        f32x4 s0 = (f32x4){0.f,0.f,0.f,0.f}, s1 = (f32x4){0.f,0.f,0.f,0.f};
        #pragma unroll
        for (int kc = 0; kc < 4; ++kc) {
            short8 b0 = *(const short8*)&k_lds[lr][kc * 32 + lg * 8];
            short8 b1 = *(const short8*)&k_lds[16 + lr][kc * 32 + lg * 8];
            s0 = MFMA16(qf[kc], b0, s0);
            s1 = MFMA16(qf[kc], b1, s1);
        }
        float resc[4];
        #pragma unroll
        for (int r = 0; r < 4; ++r) {
            float mxv = fmaxf(s0[r], s1[r]);
            #pragma unroll
            for (int m = 1; m < 16; m <<= 1) mxv = fmaxf(mxv, __shfl_xor(mxv, m));
            float mnew = fmaxf(mrun[r], mxv * scale);
            float rc = __expf(mrun[r] - mnew);
            mrun[r] = mnew;
            float p0 = __expf(s0[r] * scale - mnew);
            float p1 = __expf(s1[r] * scale - mnew);
            float rs = p0 + p1;
            #pragma unroll
            for (int m = 1; m < 16; m <<= 1) rs += __shfl_xor(rs, m);
            lrun[r] = lrun[r] * rc + rs;
            resc[r] = rc;
            p_lds[w][lg * 4 + r][lr] = f2bf(p0);
            p_lds[w][lg * 4 + r][16 + lr] = f2bf(p1);
        }
        #pragma unroll
        for (int dt = 0; dt < 8; ++dt) {
            f32x4 o = oacc[dt];
            o[0] *= resc[0]; o[1] *= resc[1]; o[2] *= resc[2]; o[3] *= resc[3];
            oacc[dt] = o;
        }
        short8 ap = *(const short8*)&p_lds[w][lr][lg * 8];
        #pragma unroll
        for (int dt = 0; dt < 8; ++dt) {
            short8 bv = *(const short8*)&vT_lds[dt * 16 + lr][lg * 8];
            oacc[dt] = MFMA16(ap, bv, oacc[dt]);
        }
        __syncthreads();
    }
    float inv[4];
    #pragma unroll
    for (int r = 0; r < 4; ++r) inv[r] = 1.0f / lrun[r];
    float* op = Og + base;
    #pragma unroll
    for (int dt = 0; dt < 8; ++dt)
        #pragma unroll
        for (int r = 0; r < 4; ++r)
            op[(size_t)(qrow0 + lg * 4 + r) * Dh + dt * 16 + lr] = oacc[dt][r] * inv[r];
}

extern "C" void kernel_launch(void* const* d_in, const int* in_sizes, int n_in,
                              void* d_out, int out_size, void* d_ws, size_t ws_size,
                              hipStream_t stream) {
    const float* q = (const float*)d_in[0];
    const float* k = (const float*)d_in[1];
    const float* v = (const float*)d_in[2];
    float* o = (float*)d_out;

    const int BH  = in_sizes[0] / (S_ * Dh);     // 32
    const int nqt = S_ / QBLK;                    // 16

    const size_t kz_bytes = (size_t)BH * S_ * Dh * sizeof(short);   // 16.78 MB
    const size_t need = 2 * kz_bytes;

    if (ws_size >= need) {
        short* Kz = (short*)d_ws;
        short* Vt = (short*)((char*)d_ws + kz_bytes);
        hipLaunchKernelGGL(prep_k, dim3(BH * S_ * 16 / 256), dim3(256), 0, stream, k, Kz);
        hipLaunchKernelGGL(prep_v, dim3(BH * (S_ / 64) * 2), dim3(256), 0, stream, v, Vt);
        hipLaunchKernelGGL(mea_fwd5, dim3(BH * nqt), dim3(256), 0, stream, q, Kz, Vt, o, nqt);
    } else {
        hipLaunchKernelGGL(mea_fwd_fb, dim3(BH * (S_ / 64)), dim3(256), 0, stream,
                           q, k, v, o, S_, S_ / 64);
    }
}

// Round 6
// 95.493 us; speedup vs baseline: 1.0191x; 1.0191x over previous
//
#include <hip/hip_runtime.h>
#include <hip/hip_bf16.h>

// MemoryEfficientAttention round 6: one-tile-deep software pipeline.
//  - triple-buffered K/V LDS (3 x 32 KB), staging runs TWO tiles ahead
//  - QK(t+1) issued at top of iter t -> its MFMAs drain while softmax(t)/pack(t)
//    run on the VALU; PV(t) follows. Per-tile critical path ~= max(MFMA, VALU)
//    instead of MFMA + VALU.
//  - 8 waves x 32 q = 256 q/block, grid 256 (1 block/CU)
//  - otherwise round-5 structure: swapped-QK 32x32 MFMA, in-register softmax,
//    permlane32_swap P-pack, defer-max, pre-transposed bf16 K/V in ws

typedef short short8 __attribute__((ext_vector_type(8)));
typedef float f32x16 __attribute__((ext_vector_type(16)));

#define MFMA32(a, b, c) __builtin_amdgcn_mfma_f32_32x32x16_bf16((a), (b), (c), 0, 0, 0)

#if __has_builtin(__builtin_amdgcn_exp2f)
#define EXP2(x) __builtin_amdgcn_exp2f(x)
#else
#define EXP2(x) exp2f(x)
#endif

constexpr int Dh  = 128;
constexpr int S_  = 2048;
constexpr int KVB = 64;
constexpr int NT  = S_ / KVB;          // 32 kv tiles
constexpr int WAVES = 8;
constexpr int QBLK  = 256;             // 8 waves x 32 q-rows

__device__ __forceinline__ short f2bf(float f) {
    union { float f; unsigned u; } x; x.f = f;
    unsigned r = x.u + 0x7fffu + ((x.u >> 16) & 1u);   // RNE
    return (short)(r >> 16);
}

// packed RNE f32x2 -> bf16x2
__device__ __forceinline__ unsigned pkbf(float lo, float hi) {
    unsigned r;
    asm("v_cvt_pk_bf16_f32 %0, %1, %2" : "=v"(r) : "v"(lo), "v"(hi));
    return r;
}

// v_permlane32_swap_b32: a.row1 <-> b.row0  (rows = lane<32 / lane>=32)
__device__ __forceinline__ void pswap(unsigned &a, unsigned &b) {
    asm("v_permlane32_swap_b32 %0, %1" : "+v"(a), "+v"(b));
}

__device__ __forceinline__ void gload16(const void* g, void* l) {
    __builtin_amdgcn_global_load_lds(
        (const __attribute__((address_space(1))) unsigned int*)g,
        (__attribute__((address_space(3))) unsigned int*)l, 16, 0, 0);
}

// ---------------- pre-pass: K fp32 -> bf16, 16B blocks XOR'd by row&15 -----
__global__ __launch_bounds__(256) void prep_k(const float* __restrict__ K,
                                              short* __restrict__ Kz) {
    int idx = blockIdx.x * 256 + threadIdx.x;     // one 16B out block
    int b   = idx & 15;
    int s   = (idx >> 4) & (S_ - 1);
    int sb  = b ^ (s & 15);
    const float* src = K + (size_t)(idx >> 4) * Dh + sb * 8;
    float4 f0 = ((const float4*)src)[0];
    float4 f1 = ((const float4*)src)[1];
    short8 o;
    o[0] = f2bf(f0.x); o[1] = f2bf(f0.y); o[2] = f2bf(f0.z); o[3] = f2bf(f0.w);
    o[4] = f2bf(f1.x); o[5] = f2bf(f1.y); o[6] = f2bf(f1.z); o[7] = f2bf(f1.w);
    *(short8*)(Kz + (size_t)idx * 8) = o;
}

// ---------------- pre-pass: V fp32 -> bf16 transposed tiles ----------------
// Vt[bh][seg][d][64]: row d holds V[seg*64 .. +63][d]; 16B block j stores
// s-block (j ^ (d&7)).
__global__ __launch_bounds__(256) void prep_v(const float* __restrict__ V,
                                              short* __restrict__ Vt) {
    __shared__ short tr[64][72];
    int bid = blockIdx.x;
    int dg = bid & 1, seg = (bid >> 1) & 31, bh = bid >> 6;
    int t = threadIdx.x;
    int s = t >> 2, d0 = (t & 3) * 16;
    const float* src = V + (size_t)(bh * S_ + seg * 64 + s) * Dh + dg * 64 + d0;
    #pragma unroll
    for (int i = 0; i < 16; i += 4) {
        float4 f = *(const float4*)(src + i);
        tr[d0 + i + 0][s] = f2bf(f.x); tr[d0 + i + 1][s] = f2bf(f.y);
        tr[d0 + i + 2][s] = f2bf(f.z); tr[d0 + i + 3][s] = f2bf(f.w);
    }
    __syncthreads();
    int d = t >> 2, j0 = (t & 3) * 2;
    size_t ob = ((size_t)(bh * 32 + seg) * 128 + dg * 64 + d) * 64;
    #pragma unroll
    for (int jj = 0; jj < 2; ++jj) {
        int j = j0 + jj;
        int sj = (j ^ (d & 7)) * 8;
        short8 val = *(const short8*)&tr[d][sj];
        *(short8*)(Vt + ob + j * 8) = val;
    }
}

// ---------------- main flash kernel (8-wave, pipelined, swapped QK) --------
__global__ __launch_bounds__(512, 2)
void mea_fwd6(const float* __restrict__ Qg, const short* __restrict__ Kz,
              const short* __restrict__ Vt, float* __restrict__ Og, int nqt) {
    __shared__ __align__(16) short kbuf[3][KVB * Dh];   // 3 x 16 KB
    __shared__ __align__(16) short vbuf[3][Dh * KVB];   // 3 x 16 KB
    __shared__ float bc_lds[WAVES][32];                  // rare-path broadcast

    // bijective XCD swizzle (grid % 8 == 0): 4 bh per XCD -> KV fits its L2
    const int bid = blockIdx.x;
    const int cpx = (int)gridDim.x >> 3;
    const int swz = (bid & 7) * cpx + (bid >> 3);
    const int qt  = swz % nqt;
    const int bh  = swz / nqt;

    const int tid  = threadIdx.x;
    const int w    = tid >> 6;
    const int lane = tid & 63;
    const int l31  = lane & 31;
    const int hi   = lane >> 5;

    const size_t base = (size_t)bh * S_ * Dh;
    const int    qrow = qt * QBLK + w * 32 + l31;   // this lane's softmax row
    const float  QSC  = 0.08838834764831845f * 1.4426950408889634f; // scale*log2e

    // ---- Q B-frags: lane holds Q[qrow][kc*16 + hi*8 .. +7], pre-scaled ----
    short8 qf[8];
    {
        const float* qp = Qg + base + (size_t)qrow * Dh;
        #pragma unroll
        for (int kc = 0; kc < 8; ++kc) {
            const float4 f0 = *(const float4*)(qp + kc * 16 + hi * 8);
            const float4 f1 = *(const float4*)(qp + kc * 16 + hi * 8 + 4);
            short8 a;
            a[0] = f2bf(f0.x * QSC); a[1] = f2bf(f0.y * QSC);
            a[2] = f2bf(f0.z * QSC); a[3] = f2bf(f0.w * QSC);
            a[4] = f2bf(f1.x * QSC); a[5] = f2bf(f1.y * QSC);
            a[6] = f2bf(f1.z * QSC); a[7] = f2bf(f1.w * QSC);
            qf[kc] = a;
        }
    }

    f32x16 oacc[4];
    #pragma unroll
    for (int dt = 0; dt < 4; ++dt)
        #pragma unroll
        for (int r = 0; r < 16; ++r) oacc[dt][r] = 0.f;
    float mrun = -1e30f, lpart = 0.f;

    const short* kt0 = Kz + base;           // [64 kv][128 d] tiles, contiguous
    const short* vt0 = Vt + base;           // [128 d][64 kv] tiles, contiguous

    // rotating LDS buffer pointers: at iter t, A = tile t, B = tile t+1, C = free
    short *kA = kbuf[0], *kB = kbuf[1], *kC = kbuf[2];
    short *vA = vbuf[0], *vB = vbuf[1], *vC = vbuf[2];

    auto STAGE = [&](short* kl, short* vl, int t) {
        const short* ks = kt0 + (size_t)t * (KVB * Dh);
        const short* vs = vt0 + (size_t)t * (Dh * KVB);
        #pragma unroll
        for (int i = 0; i < 2; ++i) {
            const int ou = (i * 8 + w) * 512;        // wave-uniform LDS offset
            gload16(ks + ou + lane * 8, kl + ou);
            gload16(vs + ou + lane * 8, vl + ou);
        }
    };

    // S^T = K Q for one 64kv x 32q tile: two 32x32 outputs (kv halves)
    auto QKSTEP = [&](const short* kl, f32x16& A, f32x16& B) {
        #pragma unroll
        for (int r = 0; r < 16; ++r) { A[r] = 0.f; B[r] = 0.f; }
        __builtin_amdgcn_s_setprio(1);
        #pragma unroll
        for (int kc = 0; kc < 8; ++kc) {
            const int go = (((kc * 2 + hi) ^ (l31 & 15)) * 8);
            const short8 a0 = *(const short8*)&kl[l31 * Dh + go];
            const short8 a1 = *(const short8*)&kl[(32 + l31) * Dh + go];
            A = MFMA32(a0, qf[kc], A);
            B = MFMA32(a1, qf[kc], B);
        }
        __builtin_amdgcn_s_setprio(0);
    };

    // online softmax (lane-local, defer-max) + pack P into PV A-frags
    auto SMPACK = [&](f32x16& sa, f32x16& sb, short8* pf) {
        float mxl = sa[0];
        #pragma unroll
        for (int r = 1; r < 16; ++r) mxl = fmaxf(mxl, sa[r]);
        #pragma unroll
        for (int r = 0; r < 16; ++r) mxl = fmaxf(mxl, sb[r]);
        if (__any(mxl > mrun + 8.0f)) {
            float mo   = fmaxf(mxl, __shfl_xor(mxl, 32));
            float mnew = fmaxf(mrun, mo);
            float rc   = EXP2(mrun - mnew);
            mrun = mnew;
            lpart *= rc;
            if (!hi) bc_lds[w][l31] = rc;
            #pragma unroll
            for (int m = 0; m < 4; ++m) {
                const float4 rcv = *(const float4*)&bc_lds[w][m * 8 + 4 * hi];
                #pragma unroll
                for (int t2 = 0; t2 < 4; ++t2) {
                    const float f = (&rcv.x)[t2];
                    #pragma unroll
                    for (int dt = 0; dt < 4; ++dt) oacc[dt][m * 4 + t2] *= f;
                }
            }
        }
        f32x16 pa, pb;
        float s0 = 0.f, s1 = 0.f;
        #pragma unroll
        for (int r = 0; r < 16; ++r) { pa[r] = EXP2(sa[r] - mrun); s0 += pa[r]; }
        #pragma unroll
        for (int r = 0; r < 16; ++r) { pb[r] = EXP2(sb[r] - mrun); s1 += pb[r]; }
        lpart += s0 + s1;
        #pragma unroll
        for (int kk = 0; kk < 2; ++kk) {
            unsigned a0 = pkbf(pa[kk * 8 + 0], pa[kk * 8 + 1]);
            unsigned a1 = pkbf(pa[kk * 8 + 2], pa[kk * 8 + 3]);
            unsigned b0 = pkbf(pa[kk * 8 + 4], pa[kk * 8 + 5]);
            unsigned b1 = pkbf(pa[kk * 8 + 6], pa[kk * 8 + 7]);
            pswap(a0, b0); pswap(a1, b1);
            unsigned wd[4] = {a0, a1, b0, b1};
            pf[kk] = *(const short8*)wd;
        }
        #pragma unroll
        for (int kk = 0; kk < 2; ++kk) {
            unsigned a0 = pkbf(pb[kk * 8 + 0], pb[kk * 8 + 1]);
            unsigned a1 = pkbf(pb[kk * 8 + 2], pb[kk * 8 + 3]);
            unsigned b0 = pkbf(pb[kk * 8 + 4], pb[kk * 8 + 5]);
            unsigned b1 = pkbf(pb[kk * 8 + 6], pb[kk * 8 + 7]);
            pswap(a0, b0); pswap(a1, b1);
            unsigned wd[4] = {a0, a1, b0, b1};
            pf[2 + kk] = *(const short8*)wd;
        }
    };

    auto PVSTEP = [&](const short* vl, const short8* pf) {
        __builtin_amdgcn_s_setprio(1);
        #pragma unroll
        for (int dt = 0; dt < 4; ++dt) {
            #pragma unroll
            for (int ks = 0; ks < 4; ++ks) {
                const short8 bv = *(const short8*)
                    &vl[(dt * 32 + l31) * KVB + (((ks * 2 + hi) ^ (l31 & 7)) * 8)];
                oacc[dt] = MFMA32(pf[ks], bv, oacc[dt]);
            }
        }
        __builtin_amdgcn_s_setprio(0);
    };

    // iter t: stage(t+2)->C; QK(t+1) from kB (MFMA drains under softmax VALU);
    // softmax+pack(t); PV(t) from vA; barrier; rotate (A,B,C)->(B,C,A)
    auto BODY = [&](int t, f32x16& cA, f32x16& cB, f32x16& nA, f32x16& nB) {
        if (t + 2 < NT) STAGE(kC, vC, t + 2);
        QKSTEP(kB, nA, nB);
        short8 pf[4];
        SMPACK(cA, cB, pf);
        PVSTEP(vA, pf);
        __syncthreads();
        short* tk = kA; kA = kB; kB = kC; kC = tk;
        short* tv = vA; vA = vB; vB = vC; vC = tv;
    };

    // ---- prologue: stage tiles 0,1; QK(0) ----
    STAGE(kA, vA, 0);
    STAGE(kB, vB, 1);
    __syncthreads();
    f32x16 s0A, s0B, s1A, s1B;
    QKSTEP(kA, s0A, s0B);

    // ---- main loop: NT-1 = 31 pipelined bodies + tail ----
    #pragma unroll 1
    for (int kk = 0; kk < 15; ++kk) {
        BODY(2 * kk,     s0A, s0B, s1A, s1B);
        BODY(2 * kk + 1, s1A, s1B, s0A, s0B);
    }
    BODY(30, s0A, s0B, s1A, s1B);
    {   // tail: tile 31 (QK already done into s1)
        short8 pf[4];
        SMPACK(s1A, s1B, pf);
        PVSTEP(vA, pf);
    }

    // ---- epilogue: total row sum via lane^32, broadcast 1/l, store ----
    {
        const float tot = lpart + __shfl_xor(lpart, 32);
        if (!hi) bc_lds[w][l31] = 1.0f / tot;
    }
    float* op = Og + base;
    #pragma unroll
    for (int m = 0; m < 4; ++m) {
        const float4 li = *(const float4*)&bc_lds[w][m * 8 + 4 * hi];
        #pragma unroll
        for (int t2 = 0; t2 < 4; ++t2) {
            const int row  = m * 8 + 4 * hi + t2;
            const float lf = (&li.x)[t2];
            #pragma unroll
            for (int dt = 0; dt < 4; ++dt)
                op[(size_t)(qt * QBLK + w * 32 + row) * Dh + dt * 32 + l31]
                    = oacc[dt][m * 4 + t2] * lf;
        }
    }
}

// ---------------- fallback (no-ws path) ------------------------------------
typedef float f32x4 __attribute__((ext_vector_type(4)));
#define MFMA16(a, b, c) __builtin_amdgcn_mfma_f32_16x16x32_bf16((a), (b), (c), 0, 0, 0)
constexpr int FKVB = 32;
constexpr int FKP  = 136;
constexpr int FVP  = 40;
constexpr int FPP  = 40;

__global__ __launch_bounds__(256, 2)
void mea_fwd_fb(const float* __restrict__ Qg, const float* __restrict__ Kg,
                const float* __restrict__ Vg, float* __restrict__ Og,
                int S, int nqt) {
    __shared__ __align__(16) short k_lds[FKVB][FKP];
    __shared__ __align__(16) short vT_lds[Dh][FVP];
    __shared__ __align__(16) short p_lds[4][16][FPP];

    const int qt = blockIdx.x % nqt;
    const int bh = blockIdx.x / nqt;
    const int tid = threadIdx.x;
    const int w = tid >> 6, lane = tid & 63;
    const int lr = lane & 15, lg = lane >> 4;
    const size_t base = (size_t)bh * S * Dh;
    const int qrow0 = qt * 64 + w * 16;
    const float scale = 0.08838834764831845f;

    short8 qf[4];
    {
        const float* qp = Qg + base + (size_t)(qrow0 + lr) * Dh;
        #pragma unroll
        for (int kc = 0; kc < 4; ++kc) {
            const float4 f0 = *(const float4*)(qp + kc * 32 + lg * 8);
            const float4 f1 = *(const float4*)(qp + kc * 32 + lg * 8 + 4);
            short8 a;
            a[0] = f2bf(f0.x); a[1] = f2bf(f0.y); a[2] = f2bf(f0.z); a[3] = f2bf(f0.w);
            a[4] = f2bf(f1.x); a[5] = f2bf(f1.y); a[6] = f2bf(f1.z); a[7] = f2bf(f1.w);
            qf[kc] = a;
        }
    }
    f32x4 oacc[8];
    #pragma unroll
    for (int dt = 0; dt < 8; ++dt) oacc[dt] = (f32x4){0.f, 0.f, 0.f, 0.f};
    float mrun[4] = {-1e30f, -1e30f, -1e30f, -1e30f};
    float lrun[4] = {0.f, 0.f, 0.f, 0.f};
    const int sr = tid >> 3, sc = (tid & 7) * 16;

    for (int kv0 = 0; kv0 < S; kv0 += FKVB) {
        {
            const float* kp = Kg + base + (size_t)(kv0 + sr) * Dh + sc;
            const float* vp = Vg + base + (size_t)(kv0 + sr) * Dh + sc;
            short8 pk0, pk1;
            float4 f0 = ((const float4*)kp)[0], f1 = ((const float4*)kp)[1];
            float4 f2 = ((const float4*)kp)[2], f3 = ((const float4*)kp)[3];
            pk0[0] = f2bf(f0.x); pk0[1] = f2bf(f0.y); pk0[2] = f2bf(f0.z); pk0[3] = f2bf(f0.w);
            pk0[4] = f2bf(f1.x); pk0[5] = f2bf(f1.y); pk0[6] = f2bf(f1.z); pk0[7] = f2bf(f1.w);
            pk1[0] = f2bf(f2.x); pk1[1] = f2bf(f2.y); pk1[2] = f2bf(f2.z); pk1[3] = f2bf(f2.w);
            pk1[4] = f2bf(f3.x); pk1[5] = f2bf(f3.y); pk1[6] = f2bf(f3.z); pk1[7] = f2bf(f3.w);
            *(short8*)&k_lds[sr][sc] = pk0;
            *(short8*)&k_lds[sr][sc + 8] = pk1;
            #pragma unroll
            for (int i = 0; i < 4; ++i) {
                float4 f = ((const float4*)vp)[i];
                vT_lds[sc + 4 * i + 0][sr] = f2bf(f.x);
                vT_lds[sc + 4 * i + 1][sr] = f2bf(f.y);
                vT_lds[sc + 4 * i + 2][sr] = f2bf(f.z);
                vT_lds[sc + 4 * i + 3][sr] = f2bf(f.w);
            }
        }
        __syncthreads();
        f32x4 s0 = (f32x4){0.f,0.f,0.f,0.f}, s1 = (f32x4){0.f,0.f,0.f,0.f};
        #pragma unroll
        for (int kc = 0; kc < 4; ++kc) {
            short8 b0 = *(const short8*)&k_lds[lr][kc * 32 + lg * 8];
            short8 b1 = *(const short8*)&k_lds[16 + lr][kc * 32 + lg * 8];
            s0 = MFMA16(qf[kc], b0, s0);
            s1 = MFMA16(qf[kc], b1, s1);
        }
        float resc[4];
        #pragma unroll
        for (int r = 0; r < 4; ++r) {
            float mxv = fmaxf(s0[r], s1[r]);
            #pragma unroll
            for (int m = 1; m < 16; m <<= 1) mxv = fmaxf(mxv, __shfl_xor(mxv, m));
            float mnew = fmaxf(mrun[r], mxv * scale);
            float rc = __expf(mrun[r] - mnew);
            mrun[r] = mnew;
            float p0 = __expf(s0[r] * scale - mnew);
            float p1 = __expf(s1[r] * scale - mnew);
            float rs = p0 + p1;
            #pragma unroll
            for (int m = 1; m < 16; m <<= 1) rs += __shfl_xor(rs, m);
            lrun[r] = lrun[r] * rc + rs;
            resc[r] = rc;
            p_lds[w][lg * 4 + r][lr] = f2bf(p0);
            p_lds[w][lg * 4 + r][16 + lr] = f2bf(p1);
        }
        #pragma unroll
        for (int dt = 0; dt < 8; ++dt) {
            f32x4 o = oacc[dt];
            o[0] *= resc[0]; o[1] *= resc[1]; o[2] *= resc[2]; o[3] *= resc[3];
            oacc[dt] = o;
        }
        short8 ap = *(const short8*)&p_lds[w][lr][lg * 8];
        #pragma unroll
        for (int dt = 0; dt < 8; ++dt) {
            short8 bv = *(const short8*)&vT_lds[dt * 16 + lr][lg * 8];
            oacc[dt] = MFMA16(ap, bv, oacc[dt]);
        }
        __syncthreads();
    }
    float inv[4];
    #pragma unroll
    for (int r = 0; r < 4; ++r) inv[r] = 1.0f / lrun[r];
    float* op = Og + base;
    #pragma unroll
    for (int dt = 0; dt < 8; ++dt)
        #pragma unroll
        for (int r = 0; r < 4; ++r)
            op[(size_t)(qrow0 + lg * 4 + r) * Dh + dt * 16 + lr] = oacc[dt][r] * inv[r];
}

extern "C" void kernel_launch(void* const* d_in, const int* in_sizes, int n_in,
                              void* d_out, int out_size, void* d_ws, size_t ws_size,
                              hipStream_t stream) {
    const float* q = (const float*)d_in[0];
    const float* k = (const float*)d_in[1];
    const float* v = (const float*)d_in[2];
    float* o = (float*)d_out;

    const int BH  = in_sizes[0] / (S_ * Dh);     // 32
    const int nqt = S_ / QBLK;                    // 8

    const size_t kz_bytes = (size_t)BH * S_ * Dh * sizeof(short);   // 16.78 MB
    const size_t need = 2 * kz_bytes;

    if (ws_size >= need) {
        short* Kz = (short*)d_ws;
        short* Vt = (short*)((char*)d_ws + kz_bytes);
        hipLaunchKernelGGL(prep_k, dim3(BH * S_ * 16 / 256), dim3(256), 0, stream, k, Kz);
        hipLaunchKernelGGL(prep_v, dim3(BH * (S_ / 64) * 2), dim3(256), 0, stream, v, Vt);
        hipLaunchKernelGGL(mea_fwd6, dim3(BH * nqt), dim3(512), 0, stream, q, Kz, Vt, o, nqt);
    } else {
        hipLaunchKernelGGL(mea_fwd_fb, dim3(BH * (S_ / 64)), dim3(256), 0, stream,
                           q, k, v, o, S_, S_ / 64);
    }
}